// Round 7
// baseline (166.664 us; speedup 1.0000x reference)
//
#include <hip/hip_runtime.h>

// Problem constants (from reference): B=4096, N_ELEM=2048, N_NODES=1024, E2=4096
#define B_SAMPLES 4096
#define N_ELEM    2048
#define N_NODES   1024
#define E2        4096
#define BLOCK     512                    // 8 waves/block; LDS caps 4 blocks/CU
#define SLOTS     32                     // max entries/node (Poisson mean 4)
#define SLOTS_ALLOC 36                   // +4 so in-chunk overrun stays in zeroed rows
#define CHUNK     4                      // k-chunk: 8 loads in flight, 1 vmcnt wait
#define S         4                      // samples per main block
#define NPT       (N_NODES / BLOCK)      // 2 nodes per thread
#define MAIN_BLOCKS (B_SAMPLES / S)      // 1024

// Workspace layout (bytes):
//   [0, 4K)        : cnt[N_NODES]                (int)
//   [4K, 4K+576K)  : ell[SLOTS_ALLOC][N_NODES]   (float4 {wx, wy, bitcast(eid), pad})
#define WS_CNT_OFF   0
#define WS_ELL_OFF   4096

// ---------------------------------------------------------------------------
// Setup A: zero ELL table + counters. (36*1024)/256 = 144 blocks.
// ---------------------------------------------------------------------------
__global__ __launch_bounds__(256) void neq_zero_kernel(
    float4* __restrict__ ell, int* __restrict__ cnt)
{
    const int i = blockIdx.x * 256 + threadIdx.x;        // 0 .. 36863
    ell[i] = make_float4(0.f, 0.f, 0.f, 0.f);
    if (i < N_NODES) cnt[i] = 0;
}

// ---------------------------------------------------------------------------
// Setup B: build transposed-ELL via global atomics (order-independent sum).
// ---------------------------------------------------------------------------
__global__ __launch_bounds__(256) void neq_build_kernel(
    const float* __restrict__ vecs, const int* __restrict__ node_ids,
    const int* __restrict__ elem_ids, int* __restrict__ cnt,
    float4* __restrict__ ell)
{
    const int j = blockIdx.x * 256 + threadIdx.x;        // 0 .. E2-1
    int nid = node_ids[j];
    int eid = elem_ids[j];
    float2 v = ((const float2*)vecs)[j];
    int slot = atomicAdd(&cnt[nid], 1);                  // device-scope
    if (slot < SLOTS) {
        ell[slot * N_NODES + nid] = make_float4(v.x, v.y, __int_as_float(eid), 0.f);
    }
}

// ---------------------------------------------------------------------------
// Main: 512 threads, one block per S=4 samples, 2 nodes/thread. Phase-2 k-loop
// chunked by 4: all 8 ELL loads issue before one vmcnt wait (breaks the
// per-iteration load->ds_read dependent chain). Chunk-granular count guard.
// ---------------------------------------------------------------------------
__global__ __launch_bounds__(BLOCK) void neq_main_kernel(
    const float* __restrict__ EA, const float* __restrict__ e,
    const float* __restrict__ q,  const float* __restrict__ r,
    const int* __restrict__ cnt, const float4* __restrict__ ell,
    float* __restrict__ out)
{
    __shared__ float4 axial4[N_ELEM];    // 32 KiB: axial4[eid] = {s0,s1,s2,s3}
    __shared__ float red[BLOCK / 64];

    const int b0 = blockIdx.x * S;
    const int t = threadIdx.x;

    // ---- phase 1: axial4[eid] = EA*e for 4 samples (coalesced dword loads) ----
#pragma unroll
    for (int i = 0; i < N_ELEM / BLOCK; ++i) {           // 4 iters
        int eid = t + i * BLOCK;
        float4 p;
        const float* EAp = EA + (size_t)b0 * N_ELEM + eid;
        const float* ep  = e  + (size_t)b0 * N_ELEM + eid;
        p.x = EAp[0 * N_ELEM] * ep[0 * N_ELEM];
        p.y = EAp[1 * N_ELEM] * ep[1 * N_ELEM];
        p.z = EAp[2 * N_ELEM] * ep[2 * N_ELEM];
        p.w = EAp[3 * N_ELEM] * ep[3 * N_ELEM];
        axial4[eid] = p;
    }

    // per-node counts (thread owns nodes t and t+512)
    int c0 = min(cnt[t], SLOTS);
    int c1 = min(cnt[t + BLOCK], SLOTS);
    int kmax = max(c0, c1);
    __syncthreads();

    // ---- phase 2: gather, chunked k-loop (8 loads in flight per chunk) ----
    float accx[NPT][S] = {};
    float accy[NPT][S] = {};
    for (int kb = 0; kb < kmax; kb += CHUNK) {
        float4 pk[NPT][CHUNK];
        // issue all loads for this chunk back-to-back (chunk-granular guard;
        // rows kb..kb+3 are zero-padded past a node's count => contribute 0)
#pragma unroll
        for (int i = 0; i < NPT; ++i) {
            int ci = (i == 0) ? c0 : c1;
            if (kb < ci) {
#pragma unroll
                for (int kk = 0; kk < CHUNK; ++kk)
                    pk[i][kk] = ell[(kb + kk) * N_NODES + t + i * BLOCK];
            } else {
#pragma unroll
                for (int kk = 0; kk < CHUNK; ++kk)
                    pk[i][kk] = make_float4(0.f, 0.f, 0.f, 0.f);
            }
        }
        // consume: ds_read_b128 gathers + FMAs
#pragma unroll
        for (int kk = 0; kk < CHUNK; ++kk) {
#pragma unroll
            for (int i = 0; i < NPT; ++i) {
                float4 w = pk[i][kk];
                int eid = __float_as_int(w.z);
                float4 ax = axial4[eid];                 // one ds_read_b128
                accx[i][0] += ax.x * w.x;  accy[i][0] += ax.x * w.y;
                accx[i][1] += ax.y * w.x;  accy[i][1] += ax.y * w.y;
                accx[i][2] += ax.z * w.x;  accy[i][2] += ax.z * w.y;
                accx[i][3] += ax.w * w.x;  accy[i][3] += ax.w * w.y;
            }
        }
    }

    // ---- phase 3: residual & sum of squares (q/r loaded late: low pressure) ----
    float acc = 0.f;
#pragma unroll
    for (int s = 0; s < S; ++s) {
        const float2* q2 = (const float2*)(q + (size_t)(b0 + s) * N_NODES * 2);
        const float2* r2 = (const float2*)(r + (size_t)(b0 + s) * N_NODES * 2);
#pragma unroll
        for (int i = 0; i < NPT; ++i) {
            int n = t + i * BLOCK;
            float2 qv = q2[n];
            float2 rv = r2[n];
            float x = accx[i][s] - qv.x - rv.x;
            float y = accy[i][s] - qv.y - rv.y;
            acc += x * x + y * y;
        }
    }

    // ---- wave + block reduce, one global atomic per block ----
#pragma unroll
    for (int off = 32; off > 0; off >>= 1)
        acc += __shfl_down(acc, off, 64);
    if ((t & 63) == 0) red[t >> 6] = acc;
    __syncthreads();
    if (t == 0) {
        float s = 0.f;
#pragma unroll
        for (int w = 0; w < BLOCK / 64; ++w) s += red[w];
        const float inv_n = 1.0f / (float)((size_t)B_SAMPLES * N_NODES * 2);
        atomicAdd(out, s * inv_n);
    }
}

extern "C" void kernel_launch(void* const* d_in, const int* in_sizes, int n_in,
                              void* d_out, int out_size, void* d_ws, size_t ws_size,
                              hipStream_t stream) {
    const float* EA       = (const float*)d_in[0];
    const float* e        = (const float*)d_in[1];
    const float* q        = (const float*)d_in[2];
    const float* r        = (const float*)d_in[3];
    const float* vecs     = (const float*)d_in[4];
    const int*   node_ids = (const int*)d_in[5];
    const int*   elem_ids = (const int*)d_in[6];

    char* ws = (char*)d_ws;
    int*    cnt = (int*)(ws + WS_CNT_OFF);
    float4* ell = (float4*)(ws + WS_ELL_OFF);

    hipMemsetAsync(d_out, 0, sizeof(float), stream);     // accumulator for fused reduce

    neq_zero_kernel<<<(SLOTS_ALLOC * N_NODES) / 256, 256, 0, stream>>>(ell, cnt);
    neq_build_kernel<<<E2 / 256, 256, 0, stream>>>(
        vecs, node_ids, elem_ids, cnt, ell);
    neq_main_kernel<<<MAIN_BLOCKS, BLOCK, 0, stream>>>(
        EA, e, q, r, cnt, ell, (float*)d_out);
}